// Round 2
// baseline (258.010 us; speedup 1.0000x reference)
//
#include <hip/hip_runtime.h>
#include <hip/hip_cooperative_groups.h>

// out[r] = dot(x[r], colsum(W)) + sum(b)
// x: [4096,4096] f32, W: [4096,4096] f32, b: [4096] f32
// ws[0..4095] = colsum(W) accumulators, ws[4096] = sum(b)

#define N 4096
#define N4 1024   // N/4 float4 columns

namespace cg = cooperative_groups;

// ---------------- fused cooperative kernel ----------------
// grid = 1024 blocks x 256 threads (4 blocks/CU on 256 CUs)
__global__ __launch_bounds__(256, 4)
void fused_kernel(const float* __restrict__ x,
                  const float* __restrict__ W,
                  const float* __restrict__ b,
                  float* __restrict__ ws,
                  float* __restrict__ out) {
    const int bid  = blockIdx.x;          // 0..1023
    const int wave = threadIdx.x >> 6;    // 0..3
    const int lane = threadIdx.x & 63;

    __shared__ float4 red[4][64];

    // ---- phase 1: column sums of W (+ bias sum) ----
    // block (s, r): stripe s of 64 float4 columns, row chunk r of 64 rows
    const int s    = bid & 15;
    const int r    = bid >> 4;
    const int col4 = s * 64 + lane;
    const float4* W4 = reinterpret_cast<const float4*>(W);

    float4 acc = make_float4(0.f, 0.f, 0.f, 0.f);
    const int row0 = r * 64 + wave * 16;
#pragma unroll
    for (int i = 0; i < 16; ++i) {
        float4 v = W4[(size_t)(row0 + i) * N4 + col4];
        acc.x += v.x; acc.y += v.y; acc.z += v.z; acc.w += v.w;
    }
    red[wave][lane] = acc;
    __syncthreads();
    if (wave == 0) {
        float4 a0 = red[0][lane], a1 = red[1][lane];
        float4 a2 = red[2][lane], a3 = red[3][lane];
        float tx = a0.x + a1.x + a2.x + a3.x;
        float ty = a0.y + a1.y + a2.y + a3.y;
        float tz = a0.z + a1.z + a2.z + a3.z;
        float tw = a0.w + a1.w + a2.w + a3.w;
        float* dst = ws + col4 * 4;       // 64 atomics per address total
        atomicAdd(dst + 0, tx);
        atomicAdd(dst + 1, ty);
        atomicAdd(dst + 2, tz);
        atomicAdd(dst + 3, tw);
    }
    if (bid < 4) {                        // bias sum: 4 blocks cover 4096 floats
        float4 bv = reinterpret_cast<const float4*>(b)[bid * 256 + threadIdx.x];
        float sb = bv.x + bv.y + bv.z + bv.w;
#pragma unroll
        for (int off = 32; off > 0; off >>= 1)
            sb += __shfl_down(sb, off, 64);
        if (lane == 0)
            atomicAdd(ws + N, sb);        // 16 atomics total
    }

    cg::this_grid().sync();

    // ---- phase 2: gemv, one wave per row ----
    const int row = bid * 4 + wave;
    const float4* x4 = reinterpret_cast<const float4*>(x) + (size_t)row * N4;
    const float4* w4 = reinterpret_cast<const float4*>(ws);

    float a = 0.f;
#pragma unroll
    for (int k = 0; k < 16; ++k) {
        float4 xv = x4[lane + k * 64];
        float4 wv = w4[lane + k * 64];    // 16 KB, L2/L3-hot
        a += xv.x * wv.x + xv.y * wv.y + xv.z * wv.z + xv.w * wv.w;
    }
#pragma unroll
    for (int off = 32; off > 0; off >>= 1)
        a += __shfl_down(a, off, 64);
    if (lane == 0)
        out[row] = a + ws[N];
}

// ---------------- fallback path (proven round-1 kernels) ----------------
__global__ void colsum_kernel(const float* __restrict__ W,
                              const float* __restrict__ b,
                              float* __restrict__ ws) {
    const int c4 = blockIdx.x * blockDim.x + threadIdx.x;
    const int row0 = blockIdx.y * 64;
    const float4* W4 = reinterpret_cast<const float4*>(W);
    float4 acc = make_float4(0.f, 0.f, 0.f, 0.f);
#pragma unroll 8
    for (int r = 0; r < 64; ++r) {
        float4 v = W4[(size_t)(row0 + r) * N4 + c4];
        acc.x += v.x; acc.y += v.y; acc.z += v.z; acc.w += v.w;
    }
    float* dst = ws + c4 * 4;
    atomicAdd(dst + 0, acc.x);
    atomicAdd(dst + 1, acc.y);
    atomicAdd(dst + 2, acc.z);
    atomicAdd(dst + 3, acc.w);
    if (blockIdx.y == 0) {
        const float4 bv = reinterpret_cast<const float4*>(b)[c4];
        float sb = bv.x + bv.y + bv.z + bv.w;
#pragma unroll
        for (int off = 32; off > 0; off >>= 1)
            sb += __shfl_down(sb, off, 64);
        if ((threadIdx.x & 63) == 0)
            atomicAdd(ws + N, sb);
    }
}

__global__ void gemv_kernel(const float* __restrict__ x,
                            const float* __restrict__ ws,
                            float* __restrict__ out) {
    const int wave = threadIdx.x >> 6;
    const int lane = threadIdx.x & 63;
    const int row  = blockIdx.x * 4 + wave;
    const float4* x4 = reinterpret_cast<const float4*>(x) + (size_t)row * N4;
    const float4* w4 = reinterpret_cast<const float4*>(ws);
    float a = 0.f;
#pragma unroll
    for (int k = 0; k < 16; ++k) {
        float4 xv = x4[lane + k * 64];
        float4 wv = w4[lane + k * 64];
        a += xv.x * wv.x + xv.y * wv.y + xv.z * wv.z + xv.w * wv.w;
    }
#pragma unroll
    for (int off = 32; off > 0; off >>= 1)
        a += __shfl_down(a, off, 64);
    if (lane == 0)
        out[row] = a + ws[N];
}

extern "C" void kernel_launch(void* const* d_in, const int* in_sizes, int n_in,
                              void* d_out, int out_size, void* d_ws, size_t ws_size,
                              hipStream_t stream) {
    const float* x = (const float*)d_in[0];
    const float* W = (const float*)d_in[1];
    const float* b = (const float*)d_in[2];
    float* out = (float*)d_out;
    float* ws  = (float*)d_ws;

    hipMemsetAsync(ws, 0, (N + 1) * sizeof(float), stream);

    void* args[] = { (void*)&x, (void*)&W, (void*)&b, (void*)&ws, (void*)&out };
    hipError_t e = hipLaunchCooperativeKernel((void*)fused_kernel,
                                              dim3(1024), dim3(256),
                                              args, 0, stream);
    if (e != hipSuccess) {
        // fallback: classic two-kernel path
        colsum_kernel<<<dim3(N4 / 256, N / 64), 256, 0, stream>>>(W, b, ws);
        gemv_kernel<<<N / 4, 256, 0, stream>>>(x, ws, out);
    }
}

// Round 5
// 147.655 us; speedup vs baseline: 1.7474x; 1.7474x over previous
//
#include <hip/hip_runtime.h>

// out[r] = dot(x[r], colsum(W)) + sum(b)
// x: [4096,4096] f32, W: [4096,4096] f32 (row-major [OUT][IN]), b: [4096] f32
// ws[0..4095] = colsum(W) accumulators, ws[4096] = sum(b)

#define N 4096
#define N4 1024   // N/4 float4 columns

// ---- column sums of W (+ bias sum) ----
// grid = 1024 blocks x 256 threads (16 col-stripes x 64 row-chunks)
// block (s, r): 64 float4-columns stripe s, 64 rows chunk r; each wave sums 16 rows,
// LDS-combine across the 4 waves, then 4 atomicAdds per lane (64 atomics/address total).
__global__ __launch_bounds__(256)
void colsum_kernel(const float* __restrict__ W,
                   const float* __restrict__ b,
                   float* __restrict__ ws) {
    const int bid  = blockIdx.x;
    const int wave = threadIdx.x >> 6;
    const int lane = threadIdx.x & 63;
    const int s    = bid & 15;            // col stripe 0..15
    const int r    = bid >> 4;            // row chunk 0..63
    const int c4   = s * 64 + lane;       // float4 col 0..1023
    const float4* W4 = reinterpret_cast<const float4*>(W);

    float4 acc = make_float4(0.f, 0.f, 0.f, 0.f);
    const int row0 = r * 64 + wave * 16;
#pragma unroll
    for (int i = 0; i < 16; ++i) {
        float4 v = W4[(size_t)(row0 + i) * N4 + c4];   // 1 KB/wave/row, coalesced
        acc.x += v.x; acc.y += v.y; acc.z += v.z; acc.w += v.w;
    }

    __shared__ float4 red[4][64];
    red[wave][lane] = acc;
    __syncthreads();
    if (wave == 0) {
        float4 a0 = red[0][lane], a1 = red[1][lane];
        float4 a2 = red[2][lane], a3 = red[3][lane];
        float* dst = ws + c4 * 4;
        atomicAdd(dst + 0, a0.x + a1.x + a2.x + a3.x);
        atomicAdd(dst + 1, a0.y + a1.y + a2.y + a3.y);
        atomicAdd(dst + 2, a0.z + a1.z + a2.z + a3.z);
        atomicAdd(dst + 3, a0.w + a1.w + a2.w + a3.w);
    }

    if (bid < 4) {                        // bias sum: 4 blocks cover 4096 floats
        float4 bv = reinterpret_cast<const float4*>(b)[bid * 256 + threadIdx.x];
        float sb = bv.x + bv.y + bv.z + bv.w;
#pragma unroll
        for (int off = 32; off > 0; off >>= 1)
            sb += __shfl_down(sb, off, 64);
        if (lane == 0)
            atomicAdd(ws + N, sb);        // 16 atomics total
    }
}

// ---- gemv: one wave per row ----
__global__ __launch_bounds__(256)
void gemv_kernel(const float* __restrict__ x,
                 const float* __restrict__ ws,
                 float* __restrict__ out) {
    const int wave = threadIdx.x >> 6;
    const int lane = threadIdx.x & 63;
    const int row  = blockIdx.x * 4 + wave;

    const float4* x4 = reinterpret_cast<const float4*>(x) + (size_t)row * N4;
    const float4* w4 = reinterpret_cast<const float4*>(ws);

    float a = 0.f;
#pragma unroll
    for (int k = 0; k < 16; ++k) {
        float4 xv = x4[lane + k * 64];    // 1 KB/wave/iter, coalesced
        float4 wv = w4[lane + k * 64];    // 16 KB, L2-hot
        a += xv.x * wv.x + xv.y * wv.y + xv.z * wv.z + xv.w * wv.w;
    }
#pragma unroll
    for (int off = 32; off > 0; off >>= 1)
        a += __shfl_down(a, off, 64);
    if (lane == 0)
        out[row] = a + ws[N];
}

extern "C" void kernel_launch(void* const* d_in, const int* in_sizes, int n_in,
                              void* d_out, int out_size, void* d_ws, size_t ws_size,
                              hipStream_t stream) {
    const float* x = (const float*)d_in[0];
    const float* W = (const float*)d_in[1];
    const float* b = (const float*)d_in[2];
    float* out = (float*)d_out;
    float* ws  = (float*)d_ws;

    hipMemsetAsync(ws, 0, (N + 1) * sizeof(float), stream);
    colsum_kernel<<<1024, 256, 0, stream>>>(W, b, ws);
    gemv_kernel<<<N / 4, 256, 0, stream>>>(x, ws, out);
}